// Round 13
// baseline (141.641 us; speedup 1.0000x reference)
//
#include <hip/hip_runtime.h>
#include <math.h>

// ---------------------------------------------------------------------------
// LatentReverb: B=2, C=4, H=64, W=64.
// k1 (reverb): column-slab redundant halo, lanes = rows, 64 blocks x 1024 thr.
//   DOUBLE-BUFFERED P in LDS; each wave re-blurs its own 3 source cols (no BL
//   plane) -> ONE barrier per iteration (8 total).
// k2 (attn): head_dim=1, 4-way key split (2048 blocks), SPLIT-LOCAL analytic
//   max + raw v_exp_f32; partial (N,D,m) to ws; exact rescaled merge in k3.
// k3: final = conv3x3 + split-softmax merge + out_proj + oc 1x1 + mix.
// ---------------------------------------------------------------------------

#define ZERO4 make_float4(0.f, 0.f, 0.f, 0.f)

__device__ __forceinline__ float sigf(float v) { return 1.0f / (1.0f + __expf(-v)); }

// lane i <- lane i-1, lane 0 <- 0   [wave_shr:1]  == value at row r-1
__device__ __forceinline__ float dppL(float v) {
    return __int_as_float(__builtin_amdgcn_mov_dpp(__float_as_int(v), 0x138, 0xf, 0xf, true));
}
// lane i <- lane i+1, lane 63 <- 0  [wave_shl:1]  == value at row r+1
__device__ __forceinline__ float dppR(float v) {
    return __int_as_float(__builtin_amdgcn_mov_dpp(__float_as_int(v), 0x130, 0xf, 0xf, true));
}
__device__ __forceinline__ float4 shL4(float4 v) {   // row r-1 (zero at r=0)
    return make_float4(dppL(v.x), dppL(v.y), dppL(v.z), dppL(v.w));
}
__device__ __forceinline__ float4 shR4(float4 v) {   // row r+1 (zero at r=63)
    return make_float4(dppR(v.x), dppR(v.y), dppR(v.z), dppR(v.w));
}

// one 3x3 tap for all 4 oc x 4 ic; wp = fb_w + ky*3 + kx  ([oc][ic][3][3])
__device__ __forceinline__ void tap(float4& a, const float4 t, const float* wp) {
    a.x += wp[0]   * t.x + wp[9]    * t.y + wp[18]    * t.z + wp[27]    * t.w;
    a.y += wp[36]  * t.x + wp[36+9] * t.y + wp[36+18] * t.z + wp[36+27] * t.w;
    a.z += wp[72]  * t.x + wp[72+9] * t.y + wp[72+18] * t.z + wp[72+27] * t.w;
    a.w += wp[108] * t.x + wp[108+9]* t.y + wp[108+18]* t.z + wp[108+27]* t.w;
}

// vertical 7-tap blur of one register-held column (rows in lanes)
__device__ __forceinline__ float4 blur7(float4 v, const float* kv) {
    const float4 l1 = shL4(v),  l2 = shL4(l1), l3 = shL4(l2);
    const float4 r1 = shR4(v),  r2 = shR4(r1), r3 = shR4(r2);
    float4 b;
    b.x = kv[0]*l3.x + kv[1]*l2.x + kv[2]*l1.x + kv[3]*v.x
        + kv[4]*r1.x + kv[5]*r2.x + kv[6]*r3.x;
    b.y = kv[0]*l3.y + kv[1]*l2.y + kv[2]*l1.y + kv[3]*v.y
        + kv[4]*r1.y + kv[5]*r2.y + kv[6]*r3.y;
    b.z = kv[0]*l3.z + kv[1]*l2.z + kv[2]*l1.z + kv[3]*v.z
        + kv[4]*r1.z + kv[5]*r2.z + kv[6]*r3.z;
    b.w = kv[0]*l3.w + kv[1]*l2.w + kv[2]*l1.w + kv[3]*v.w
        + kv[4]*r1.w + kv[5]*r2.w + kv[6]*r3.w;
    return b;
}

__global__ __launch_bounds__(1024, 1) void reverb_qkv_kernel(
    const float* __restrict__ x,
    const float* __restrict__ refl_w,
    const float* __restrict__ refl_d,
    const float* __restrict__ fb_w,
    const float* __restrict__ fb_b,
    const float* __restrict__ d1_w,
    const float* __restrict__ d1_b,
    const float* __restrict__ d2_w,
    const float* __restrict__ d2_b,
    const float* __restrict__ ipw,
    const float* __restrict__ ipb,
    float* __restrict__ Qg, float* __restrict__ Kg, float* __restrict__ Vg)
{
    __shared__ float4 PA[18 * 64];    // fb plane buffer A (col-major)
    __shared__ float4 PB[18 * 64];    // fb plane buffer B
    __shared__ float4 WT[2 * 64];     // wet for the 2 owned cols
    __shared__ float  GT[3][8];       // gaussian tables

    const int blk   = blockIdx.x;
    const int batch = blk >> 5;          // 0..1
    const int own0  = (blk & 31) << 1;   // owned cols [own0, own0+2)
    const int LB    = own0 - 8;          // global col of local col 0
    const int tid   = threadIdx.x;
    const int wy    = tid >> 6;          // wave 0..15
    const int r     = tid & 63;          // lane == row

    // Gaussian tables (fp64, matches numpy K_TABLE after f32 rounding).
    if (tid < 3) {
        const int rr = tid + 1;
        const int ks = 2 * rr + 1;
        const int s  = (7 - ks) >> 1;
        const double step = 4.0 / (double)(ks - 1);
        double g[7]; double sum = 0.0;
        for (int t = 0; t < 7; ++t) {
            if (t < ks) { double u = -2.0 + step * (double)t; g[t] = exp(-u * u); sum += g[t]; }
        }
        for (int t = 0; t < 7; ++t) GT[tid][t] = 0.0f;
        for (int t = 0; t < ks; ++t) GT[tid][s + t] = (float)(g[t] / sum);
    }

    // stage fb0 = 0.1*x into BOTH buffers' col-major planes (zeros outside
    // image; those cols are never written again -> stay zero in both buffers)
    for (int idx = tid; idx < 18 * 64; idx += 1024) {
        const int lc  = idx >> 6;
        const int row = idx & 63;
        const int gc  = LB + lc;
        float4 v = ZERO4;
        if (gc >= 0 && gc < 64) {
            const int base = batch * 16384 + row * 64 + gc;
            v.x = 0.1f * x[base];
            v.y = 0.1f * x[base + 4096];
            v.z = 0.1f * x[base + 8192];
            v.w = 0.1f * x[base + 12288];
        }
        PA[idx] = v;
        PB[idx] = v;
    }
    __syncthreads();

    double w8 = 1.0;
    for (int j = 0; j < 8; ++j) {
        const float4* Pold = (j & 1) ? PB : PA;
        float4*       Pnew = (j & 1) ? PA : PB;

        int kidx = (int)floorf(refl_d[j] * 0.5f);
        kidx = kidx < 0 ? 0 : (kidx > 3 ? 3 : kidx);
        float kv[7];
        #pragma unroll
        for (int u = 0; u < 7; ++u) {
            const float dv = (u == 3) ? 1.0f : 0.0f;
            kv[u] = (kidx == 0) ? dv : GT[kidx - 1][u];
        }
        const float wgt = sigf(refl_w[j]) * (float)w8;

        const int clo = max(0, own0 - (7 - j));
        const int chi = min(64, own0 + 2 + (7 - j));   // conv cols [clo, chi)

        const int c = clo + wy;                 // one col per wave
        if (wy < chi - clo) {                   // wave-uniform
            const int lc = c - LB;              // 1..16

            // re-blur the 3 source cols from Pold (zero outside image)
            const float4 bm = (c - 1 >= 0) ? blur7(Pold[(lc - 1) * 64 + r], kv) : ZERO4;
            const float4 bc = blur7(Pold[lc * 64 + r], kv);        // c valid
            const float4 bp = (c + 1 < 64) ? blur7(Pold[(lc + 1) * 64 + r], kv) : ZERO4;

            float4 acc = make_float4(fb_b[0], fb_b[1], fb_b[2], fb_b[3]);
            tap(acc, shL4(bm), fb_w + 0);  tap(acc, shL4(bc), fb_w + 1);  tap(acc, shL4(bp), fb_w + 2);
            tap(acc, bm,       fb_w + 3);  tap(acc, bc,       fb_w + 4);  tap(acc, bp,       fb_w + 5);
            tap(acc, shR4(bm), fb_w + 6);  tap(acc, shR4(bc), fb_w + 7);  tap(acc, shR4(bp), fb_w + 8);

            // damp MLP
            float4 rr = acc;
            float h0 = d1_b[0] + d1_w[0]*rr.x + d1_w[1]*rr.y + d1_w[2]*rr.z + d1_w[3]*rr.w;
            float h1 = d1_b[1] + d1_w[4]*rr.x + d1_w[5]*rr.y + d1_w[6]*rr.z + d1_w[7]*rr.w;
            h0 = h0 * sigf(h0);
            h1 = h1 * sigf(h1);
            const float d0  = sigf(d2_b[0] + d2_w[0]*h0 + d2_w[1]*h1);
            const float d1v = sigf(d2_b[1] + d2_w[2]*h0 + d2_w[3]*h1);
            const float d2v = sigf(d2_b[2] + d2_w[4]*h0 + d2_w[5]*h1);
            const float d3v = sigf(d2_b[3] + d2_w[6]*h0 + d2_w[7]*h1);
            rr.x *= d0; rr.y *= d1v; rr.z *= d2v; rr.w *= d3v;

            // fb update: Pnew[lc] = Pold[lc] + 0.04*r  (skip dead last write)
            if (j < 7) {
                const float4 oldfb = Pold[lc * 64 + r];
                Pnew[lc * 64 + r] = make_float4(oldfb.x + 0.04f*rr.x, oldfb.y + 0.04f*rr.y,
                                                oldfb.z + 0.04f*rr.z, oldfb.w + 0.04f*rr.w);
            }

            // wet update for owned cols
            if (c >= own0 && c < own0 + 2) {
                const int widx = (c - own0) * 64 + r;
                float4 wv = make_float4(wgt*rr.x, wgt*rr.y, wgt*rr.z, wgt*rr.w);
                if (j > 0) {
                    const float4 old = WT[widx];
                    wv.x += old.x; wv.y += old.y; wv.z += old.z; wv.w += old.w;
                }
                WT[widx] = wv;
            }
        }
        __syncthreads();                        // ONE barrier per iteration
        w8 *= 0.8;
    }

    // ---- epilogue: qkv = in_proj(wet) for the 2 owned cols ----
    if (tid < 128) {
        const int row = tid & 63;
        const int oc  = tid >> 6;
        const int c   = own0 + oc;
        const float4 wv = WT[oc * 64 + row];
        #pragma unroll
        for (int h = 0; h < 4; ++h) {
            const float q = ipb[h]
                + ipw[h*4+0]*wv.x + ipw[h*4+1]*wv.y
                + ipw[h*4+2]*wv.z + ipw[h*4+3]*wv.w;
            const float k = ipb[4+h]
                + ipw[(4+h)*4+0]*wv.x + ipw[(4+h)*4+1]*wv.y
                + ipw[(4+h)*4+2]*wv.z + ipw[(4+h)*4+3]*wv.w;
            const float v = ipb[8+h]
                + ipw[(8+h)*4+0]*wv.x + ipw[(8+h)*4+1]*wv.y
                + ipw[(8+h)*4+2]*wv.z + ipw[(8+h)*4+3]*wv.w;
            const int o = (batch * 4 + h) * 4096 + row * 64 + c;
            Qg[o] = q; Kg[o] = k; Vg[o] = v;
        }
    }
}

// 2048 blocks x 256 thr: (bh, qchunk, ksplit). Split-LOCAL analytic max over
// this block's 1024 keys (4 loads/thread); SGPR key stream; raw v_exp_f32.
// Writes partial (N, D, m2) to ws; exact rescaled merge happens in final.
__global__ __launch_bounds__(256) void attn_kernel(
    const float* __restrict__ Qg, const float* __restrict__ Kg,
    const float* __restrict__ Vg,
    float* __restrict__ PN, float* __restrict__ PD, float* __restrict__ PM)
{
    __shared__ float wred[8];
    __shared__ float partN[256], partD[256];

    const int bh  = blockIdx.x >> 8;          // 0..7
    const int sub = (blockIdx.x >> 2) & 63;   // query chunk
    const int ks  = blockIdx.x & 3;           // key split
    const int tid = threadIdx.x;

    const float* Kp = Kg + bh * 4096 + ks * 1024;
    const float* Vp = Vg + bh * 4096 + ks * 1024;

    // split-local kmax/kmin (1024 keys, 4 loads/thread)
    float pmax = -3.0e38f, pmin = 3.0e38f;
    #pragma unroll
    for (int t = tid; t < 1024; t += 256) {
        const float kk = Kp[t];
        pmax = fmaxf(pmax, kk);
        pmin = fminf(pmin, kk);
    }
    #pragma unroll
    for (int off = 32; off > 0; off >>= 1) {
        pmax = fmaxf(pmax, __shfl_xor(pmax, off, 64));
        pmin = fminf(pmin, __shfl_xor(pmin, off, 64));
    }
    if ((tid & 63) == 0) { wred[tid >> 6] = pmax; wred[4 + (tid >> 6)] = pmin; }
    __syncthreads();
    const float kmax = fmaxf(fmaxf(wred[0], wred[1]), fmaxf(wred[2], wred[3]));
    const float kmin = fminf(fminf(wred[4], wred[5]), fminf(wred[6], wred[7]));

    const int ql = tid & 63;
    const int kh = __builtin_amdgcn_readfirstlane(tid >> 6);   // wave 0..3
    const int qi = sub * 64 + ql;

    const float L2E = 1.4426950408889634f;
    const float q  = Qg[bh * 4096 + qi];
    const float q2 = q * L2E;
    const float m2 = ((q >= 0.0f) ? q * kmax : q * kmin) * L2E;  // local max*L2E
    const float nm2 = -m2;

    const float4* K4 = (const float4*)Kp;
    const float4* V4 = (const float4*)Vp;
    const int base = kh * 64;                  // this wave: 256 keys

    float num0 = 0.f, num1 = 0.f, den0 = 0.f, den1 = 0.f;
    #pragma unroll 4
    for (int j = 0; j < 64; j += 2) {
        const float4 ka = K4[base + j];        // uniform -> s_load_dwordx4
        const float4 kb = K4[base + j + 1];
        const float4 va = V4[base + j];
        const float4 vb = V4[base + j + 1];
        float e;
        e = __builtin_amdgcn_exp2f(__fmaf_rn(q2, ka.x, nm2)); den0 += e; num0 = __fmaf_rn(e, va.x, num0);
        e = __builtin_amdgcn_exp2f(__fmaf_rn(q2, ka.y, nm2)); den1 += e; num1 = __fmaf_rn(e, va.y, num1);
        e = __builtin_amdgcn_exp2f(__fmaf_rn(q2, ka.z, nm2)); den0 += e; num0 = __fmaf_rn(e, va.z, num0);
        e = __builtin_amdgcn_exp2f(__fmaf_rn(q2, ka.w, nm2)); den1 += e; num1 = __fmaf_rn(e, va.w, num1);
        e = __builtin_amdgcn_exp2f(__fmaf_rn(q2, kb.x, nm2)); den0 += e; num0 = __fmaf_rn(e, vb.x, num0);
        e = __builtin_amdgcn_exp2f(__fmaf_rn(q2, kb.y, nm2)); den1 += e; num1 = __fmaf_rn(e, vb.y, num1);
        e = __builtin_amdgcn_exp2f(__fmaf_rn(q2, kb.z, nm2)); den0 += e; num0 = __fmaf_rn(e, vb.z, num0);
        e = __builtin_amdgcn_exp2f(__fmaf_rn(q2, kb.w, nm2)); den1 += e; num1 = __fmaf_rn(e, vb.w, num1);
    }
    partN[tid] = num0 + num1;
    partD[tid] = den0 + den1;
    __syncthreads();
    if (tid < 64) {
        const float n = partN[tid] + partN[tid + 64] + partN[tid + 128] + partN[tid + 192];
        const float d = partD[tid] + partD[tid + 64] + partD[tid + 128] + partD[tid + 192];
        const int o = bh * 16384 + ks * 4096 + sub * 64 + tid;   // [bh][ks][q]
        PN[o] = n;
        PD[o] = d;
        PM[o] = m2;    // this thread's own q -> its own m2
    }
}

__global__ __launch_bounds__(128) void final_kernel(
    const float* __restrict__ x,
    const float* __restrict__ sc_w, const float* __restrict__ sc_b,
    const float* __restrict__ opw,  const float* __restrict__ opb,
    const float* __restrict__ ocw,  const float* __restrict__ ocb,
    const float* __restrict__ PN,   const float* __restrict__ PD,
    const float* __restrict__ PM,   float* __restrict__ out)
{
    const int g   = blockIdx.x * 128 + threadIdx.x;   // 0..8191
    const int b   = g >> 12;
    const int pix = g & 4095;
    const int y   = pix >> 6;
    const int xc  = pix & 63;

    float xin[4][3][3];
    #pragma unroll
    for (int ic = 0; ic < 4; ++ic)
        #pragma unroll
        for (int ky = 0; ky < 3; ++ky)
            #pragma unroll
            for (int kx = 0; kx < 3; ++kx) {
                const int yy = y + ky - 1, xx = xc + kx - 1;
                xin[ic][ky][kx] = (yy >= 0 && yy < 64 && xx >= 0 && xx < 64)
                                    ? x[(b * 4 + ic) * 4096 + yy * 64 + xx] : 0.f;
            }

    float sp[8];
    #pragma unroll
    for (int oc = 0; oc < 8; ++oc) {
        float a = sc_b[oc];
        #pragma unroll
        for (int ic = 0; ic < 4; ++ic)
            #pragma unroll
            for (int ky = 0; ky < 3; ++ky)
                #pragma unroll
                for (int kx = 0; kx < 3; ++kx)
                    a += sc_w[(oc * 4 + ic) * 9 + ky * 3 + kx] * xin[ic][ky][kx];
        sp[oc] = a;
    }

    // split-softmax merge: o = sum_s N_s 2^(m_s-M) / sum_s D_s 2^(m_s-M)
    float oh[4];
    #pragma unroll
    for (int h = 0; h < 4; ++h) {
        const int bh = b * 4 + h;
        float m2s[4];
        #pragma unroll
        for (int ks = 0; ks < 4; ++ks) m2s[ks] = PM[bh * 16384 + ks * 4096 + pix];
        const float M2 = fmaxf(fmaxf(m2s[0], m2s[1]), fmaxf(m2s[2], m2s[3]));
        float n = 0.f, d = 0.f;
        #pragma unroll
        for (int ks = 0; ks < 4; ++ks) {
            const float s = __builtin_amdgcn_exp2f(m2s[ks] - M2);   // <= 0 arg
            n = __fmaf_rn(PN[bh * 16384 + ks * 4096 + pix], s, n);
            d = __fmaf_rn(PD[bh * 16384 + ks * 4096 + pix], s, d);
        }
        oh[h] = n / d;
    }

    float w2[4];
    #pragma unroll
    for (int c = 0; c < 4; ++c)
        w2[c] = opb[c] + opw[c*4+0]*oh[0] + opw[c*4+1]*oh[1]
                       + opw[c*4+2]*oh[2] + opw[c*4+3]*oh[3];

    #pragma unroll
    for (int c = 0; c < 4; ++c) {
        float a = ocb[c];
        #pragma unroll
        for (int j = 0; j < 8; ++j) a += ocw[c * 12 + j] * sp[j];
        #pragma unroll
        for (int h = 0; h < 4; ++h) a += ocw[c * 12 + 8 + h] * w2[h];
        const int idx = (b * 4 + c) * 4096 + y * 64 + xc;
        out[idx] = 0.7f * x[idx] + 0.3f * a;
    }
}

extern "C" void kernel_launch(void* const* d_in, const int* in_sizes, int n_in,
                              void* d_out, int out_size, void* d_ws, size_t ws_size,
                              hipStream_t stream) {
    const float* x      = (const float*)d_in[0];
    const float* refl_w = (const float*)d_in[1];
    const float* refl_d = (const float*)d_in[2];
    const float* sc_w   = (const float*)d_in[3];
    const float* sc_b   = (const float*)d_in[4];
    const float* fb_w   = (const float*)d_in[5];
    const float* fb_b   = (const float*)d_in[6];
    const float* d1_w   = (const float*)d_in[7];
    const float* d1_b   = (const float*)d_in[8];
    const float* d2_w   = (const float*)d_in[9];
    const float* d2_b   = (const float*)d_in[10];
    const float* ipw    = (const float*)d_in[11];
    const float* ipb    = (const float*)d_in[12];
    const float* opw    = (const float*)d_in[13];
    const float* opb    = (const float*)d_in[14];
    const float* ocw    = (const float*)d_in[15];
    const float* ocb    = (const float*)d_in[16];
    float* out = (float*)d_out;

    // ws: Q | K | V (32768 each) | PN | PD | PM (131072 each)
    float* Q  = (float*)d_ws;
    float* K  = Q + 32768;
    float* V  = K + 32768;
    float* PN = V + 32768;
    float* PD = PN + 131072;
    float* PM = PD + 131072;

    reverb_qkv_kernel<<<dim3(64), dim3(1024), 0, stream>>>(
        x, refl_w, refl_d, fb_w, fb_b, d1_w, d1_b, d2_w, d2_b, ipw, ipb,
        Q, K, V);
    attn_kernel<<<dim3(2048), dim3(256), 0, stream>>>(Q, K, V, PN, PD, PM);
    final_kernel<<<dim3(64), dim3(128), 0, stream>>>(
        x, sc_w, sc_b, opw, opb, ocw, ocb, PN, PD, PM, out);
}

// Round 14
// 136.923 us; speedup vs baseline: 1.0345x; 1.0345x over previous
//
#include <hip/hip_runtime.h>
#include <math.h>

// ---------------------------------------------------------------------------
// LatentReverb: B=2, C=4, H=64, W=64.
// k1 (reverb): R12-exact column-slab redundant halo, 64 blocks x 1024 thr.
// k2 (attn): head_dim=1, 4-way key split (2048 blocks = 8 blk/CU, occupancy
//   cap). Each block stages its 1024-key split into LDS as interleaved (k,v)
//   -> in-order ds_read stream (fine-grained lgkmcnt, unlike out-of-order
//   SMEM). Split-local analytic max + raw v_exp_f32; partial (N,D,m) to ws.
// k3: final = conv3x3 + split-softmax rescaled merge + out_proj + oc + mix.
// ---------------------------------------------------------------------------

#define ZERO4 make_float4(0.f, 0.f, 0.f, 0.f)

__device__ __forceinline__ float sigf(float v) { return 1.0f / (1.0f + __expf(-v)); }

// lane i <- lane i-1, lane 0 <- 0   [wave_shr:1]  == value at row r-1
__device__ __forceinline__ float dppL(float v) {
    return __int_as_float(__builtin_amdgcn_mov_dpp(__float_as_int(v), 0x138, 0xf, 0xf, true));
}
// lane i <- lane i+1, lane 63 <- 0  [wave_shl:1]  == value at row r+1
__device__ __forceinline__ float dppR(float v) {
    return __int_as_float(__builtin_amdgcn_mov_dpp(__float_as_int(v), 0x130, 0xf, 0xf, true));
}
__device__ __forceinline__ float4 shL4(float4 v) {   // row r-1 (zero at r=0)
    return make_float4(dppL(v.x), dppL(v.y), dppL(v.z), dppL(v.w));
}
__device__ __forceinline__ float4 shR4(float4 v) {   // row r+1 (zero at r=63)
    return make_float4(dppR(v.x), dppR(v.y), dppR(v.z), dppR(v.w));
}

// one 3x3 tap for all 4 oc x 4 ic; wp = fb_w + ky*3 + kx  ([oc][ic][3][3])
__device__ __forceinline__ void tap(float4& a, const float4 t, const float* wp) {
    a.x += wp[0]   * t.x + wp[9]    * t.y + wp[18]    * t.z + wp[27]    * t.w;
    a.y += wp[36]  * t.x + wp[36+9] * t.y + wp[36+18] * t.z + wp[36+27] * t.w;
    a.z += wp[72]  * t.x + wp[72+9] * t.y + wp[72+18] * t.z + wp[72+27] * t.w;
    a.w += wp[108] * t.x + wp[108+9]* t.y + wp[108+18]* t.z + wp[108+27]* t.w;
}

__global__ __launch_bounds__(1024, 1) void reverb_qkv_kernel(
    const float* __restrict__ x,
    const float* __restrict__ refl_w,
    const float* __restrict__ refl_d,
    const float* __restrict__ fb_w,
    const float* __restrict__ fb_b,
    const float* __restrict__ d1_w,
    const float* __restrict__ d1_b,
    const float* __restrict__ d2_w,
    const float* __restrict__ d2_b,
    const float* __restrict__ ipw,
    const float* __restrict__ ipb,
    float* __restrict__ Qg, float* __restrict__ Kg, float* __restrict__ Vg)
{
    __shared__ float4 P [18 * 64];    // fb plane, local col-major: P[lc][row]
    __shared__ float4 BL[18 * 64];    // blurred plane
    __shared__ float4 WT[2 * 64];     // wet for the 2 owned cols
    __shared__ float  GT[3][8];       // gaussian tables

    const int blk   = blockIdx.x;
    const int batch = blk >> 5;          // 0..1
    const int own0  = (blk & 31) << 1;   // owned cols [own0, own0+2)
    const int LB    = own0 - 8;          // global col of local col 0
    const int tid   = threadIdx.x;
    const int wy    = tid >> 6;          // wave 0..15
    const int r     = tid & 63;          // lane == row

    // Gaussian tables (fp64, matches numpy K_TABLE after f32 rounding).
    if (tid < 3) {
        const int rr = tid + 1;
        const int ks = 2 * rr + 1;
        const int s  = (7 - ks) >> 1;
        const double step = 4.0 / (double)(ks - 1);
        double g[7]; double sum = 0.0;
        for (int t = 0; t < 7; ++t) {
            if (t < ks) { double u = -2.0 + step * (double)t; g[t] = exp(-u * u); sum += g[t]; }
        }
        for (int t = 0; t < 7; ++t) GT[tid][t] = 0.0f;
        for (int t = 0; t < ks; ++t) GT[tid][s + t] = (float)(g[t] / sum);
    }

    // stage fb0 = 0.1*x, transposed into col-major local plane (zeros outside)
    for (int idx = tid; idx < 18 * 64; idx += 1024) {
        const int lc  = idx >> 6;
        const int row = idx & 63;
        const int gc  = LB + lc;
        float4 v = ZERO4;
        if (gc >= 0 && gc < 64) {
            const int base = batch * 16384 + row * 64 + gc;
            v.x = 0.1f * x[base];
            v.y = 0.1f * x[base + 4096];
            v.z = 0.1f * x[base + 8192];
            v.w = 0.1f * x[base + 12288];
        }
        P[idx] = v;
    }
    __syncthreads();

    double w8 = 1.0;
    for (int j = 0; j < 8; ++j) {
        int kidx = (int)floorf(refl_d[j] * 0.5f);
        kidx = kidx < 0 ? 0 : (kidx > 3 ? 3 : kidx);
        float kv[7];
        #pragma unroll
        for (int u = 0; u < 7; ++u) {
            const float dv = (u == 3) ? 1.0f : 0.0f;
            kv[u] = (kidx == 0) ? dv : GT[kidx - 1][u];
        }
        const float wgt = sigf(refl_w[j]) * (float)w8;

        const int clo = max(0, own0 - (7 - j));
        const int chi = min(64, own0 + 2 + (7 - j));

        // ---- blur phase: only cols [clo-1, chi+1) ----
        const int lcA   = (clo - 1) - LB;            // >= 0
        const int nBlur = (chi + 1) - (clo - 1);     // <= 18
        for (int t = wy; t < nBlur; t += 16) {
            const int lc = lcA + t;
            const int gc = LB + lc;
            float4 b = ZERO4;
            if (gc >= 0 && gc < 64) {
                const float4 v  = P[lc * 64 + r];
                const float4 l1 = shL4(v),  l2 = shL4(l1), l3 = shL4(l2);
                const float4 r1 = shR4(v),  r2 = shR4(r1), r3 = shR4(r2);
                b.x = kv[0]*l3.x + kv[1]*l2.x + kv[2]*l1.x + kv[3]*v.x
                    + kv[4]*r1.x + kv[5]*r2.x + kv[6]*r3.x;
                b.y = kv[0]*l3.y + kv[1]*l2.y + kv[2]*l1.y + kv[3]*v.y
                    + kv[4]*r1.y + kv[5]*r2.y + kv[6]*r3.y;
                b.z = kv[0]*l3.z + kv[1]*l2.z + kv[2]*l1.z + kv[3]*v.z
                    + kv[4]*r1.z + kv[5]*r2.z + kv[6]*r3.z;
                b.w = kv[0]*l3.w + kv[1]*l2.w + kv[2]*l1.w + kv[3]*v.w
                    + kv[4]*r1.w + kv[5]*r2.w + kv[6]*r3.w;
            }
            BL[lc * 64 + r] = b;
        }
        __syncthreads();

        // ---- conv+MLP phase: <=1 col per wave ----
        const int c = clo + wy;
        if (wy < chi - clo) {                    // wave-uniform
            const int lc = c - LB;               // 1..16
            const float4 bm = BL[(lc - 1) * 64 + r];
            const float4 bc = BL[lc * 64 + r];
            const float4 bp = BL[(lc + 1) * 64 + r];

            float4 acc = make_float4(fb_b[0], fb_b[1], fb_b[2], fb_b[3]);
            tap(acc, shL4(bm), fb_w + 0);  tap(acc, shL4(bc), fb_w + 1);  tap(acc, shL4(bp), fb_w + 2);
            tap(acc, bm,       fb_w + 3);  tap(acc, bc,       fb_w + 4);  tap(acc, bp,       fb_w + 5);
            tap(acc, shR4(bm), fb_w + 6);  tap(acc, shR4(bc), fb_w + 7);  tap(acc, shR4(bp), fb_w + 8);

            // damp MLP
            float4 rr = acc;
            float h0 = d1_b[0] + d1_w[0]*rr.x + d1_w[1]*rr.y + d1_w[2]*rr.z + d1_w[3]*rr.w;
            float h1 = d1_b[1] + d1_w[4]*rr.x + d1_w[5]*rr.y + d1_w[6]*rr.z + d1_w[7]*rr.w;
            h0 = h0 * sigf(h0);
            h1 = h1 * sigf(h1);
            const float d0  = sigf(d2_b[0] + d2_w[0]*h0 + d2_w[1]*h1);
            const float d1v = sigf(d2_b[1] + d2_w[2]*h0 + d2_w[3]*h1);
            const float d2v = sigf(d2_b[2] + d2_w[4]*h0 + d2_w[5]*h1);
            const float d3v = sigf(d2_b[3] + d2_w[6]*h0 + d2_w[7]*h1);
            rr.x *= d0; rr.y *= d1v; rr.z *= d2v; rr.w *= d3v;

            // fb update (in place; only this wave touches col lc this phase)
            const float4 oldfb = P[lc * 64 + r];
            P[lc * 64 + r] = make_float4(oldfb.x + 0.04f*rr.x, oldfb.y + 0.04f*rr.y,
                                         oldfb.z + 0.04f*rr.z, oldfb.w + 0.04f*rr.w);

            // wet update for owned cols
            if (c >= own0 && c < own0 + 2) {
                const int widx = (c - own0) * 64 + r;
                float4 wv = make_float4(wgt*rr.x, wgt*rr.y, wgt*rr.z, wgt*rr.w);
                if (j > 0) {
                    const float4 old = WT[widx];
                    wv.x += old.x; wv.y += old.y; wv.z += old.z; wv.w += old.w;
                }
                WT[widx] = wv;
            }
        }
        __syncthreads();
        w8 *= 0.8;
    }

    // ---- epilogue: qkv = in_proj(wet) for the 2 owned cols ----
    if (tid < 128) {
        const int row = tid & 63;
        const int oc  = tid >> 6;
        const int c   = own0 + oc;
        const float4 wv = WT[oc * 64 + row];
        #pragma unroll
        for (int h = 0; h < 4; ++h) {
            const float q = ipb[h]
                + ipw[h*4+0]*wv.x + ipw[h*4+1]*wv.y
                + ipw[h*4+2]*wv.z + ipw[h*4+3]*wv.w;
            const float k = ipb[4+h]
                + ipw[(4+h)*4+0]*wv.x + ipw[(4+h)*4+1]*wv.y
                + ipw[(4+h)*4+2]*wv.z + ipw[(4+h)*4+3]*wv.w;
            const float v = ipb[8+h]
                + ipw[(8+h)*4+0]*wv.x + ipw[(8+h)*4+1]*wv.y
                + ipw[(8+h)*4+2]*wv.z + ipw[(8+h)*4+3]*wv.w;
            const int o = (batch * 4 + h) * 4096 + row * 64 + c;
            Qg[o] = q; Kg[o] = k; Vg[o] = v;
        }
    }
}

// 2048 blocks x 256 thr: (bh, qchunk, ksplit). This block's 1024-key split
// staged in LDS as interleaved (k,v) float2 -> in-order ds_read stream.
// Split-local analytic max; raw v_exp_f32; partial (N, D, m2) to ws.
__global__ __launch_bounds__(256) void attn_kernel(
    const float* __restrict__ Qg, const float* __restrict__ Kg,
    const float* __restrict__ Vg,
    float* __restrict__ PN, float* __restrict__ PD, float* __restrict__ PM)
{
    __shared__ float2 KV[1024];               // 8 KB interleaved (k,v)
    __shared__ float  wred[8];
    __shared__ float  partN[256], partD[256];

    const int bh  = blockIdx.x >> 8;          // 0..7
    const int sub = (blockIdx.x >> 2) & 63;   // query chunk
    const int ks  = blockIdx.x & 3;           // key split
    const int tid = threadIdx.x;

    const float* Kp = Kg + bh * 4096 + ks * 1024;
    const float* Vp = Vg + bh * 4096 + ks * 1024;

    // stage split into LDS + split-local kmax/kmin (same scan order as R13)
    float pmax = -3.0e38f, pmin = 3.0e38f;
    #pragma unroll
    for (int t = tid; t < 1024; t += 256) {
        const float kk = Kp[t];
        const float vv = Vp[t];
        KV[t] = make_float2(kk, vv);
        pmax = fmaxf(pmax, kk);
        pmin = fminf(pmin, kk);
    }
    #pragma unroll
    for (int off = 32; off > 0; off >>= 1) {
        pmax = fmaxf(pmax, __shfl_xor(pmax, off, 64));
        pmin = fminf(pmin, __shfl_xor(pmin, off, 64));
    }
    if ((tid & 63) == 0) { wred[tid >> 6] = pmax; wred[4 + (tid >> 6)] = pmin; }
    __syncthreads();
    const float kmax = fmaxf(fmaxf(wred[0], wred[1]), fmaxf(wred[2], wred[3]));
    const float kmin = fminf(fminf(wred[4], wred[5]), fminf(wred[6], wred[7]));

    const int ql = tid & 63;
    const int kh = __builtin_amdgcn_readfirstlane(tid >> 6);   // wave 0..3
    const int qi = sub * 64 + ql;

    const float L2E = 1.4426950408889634f;
    const float q  = Qg[bh * 4096 + qi];
    const float q2 = q * L2E;
    const float m2 = ((q >= 0.0f) ? q * kmax : q * kmin) * L2E;  // local max*L2E
    const float nm2 = -m2;

    // per-wave 256 keys = 128 float4 of (k0,v0,k1,v1)
    const float4* KV4 = (const float4*)KV;
    const int base4 = kh * 128;

    float num0 = 0.f, num1 = 0.f, den0 = 0.f, den1 = 0.f;
    #pragma unroll 8
    for (int j = 0; j < 128; ++j) {
        const float4 f = KV4[base4 + j];      // broadcast ds_read_b128
        const float e0 = __builtin_amdgcn_exp2f(__fmaf_rn(q2, f.x, nm2));
        den0 += e0;  num0 = __fmaf_rn(e0, f.y, num0);
        const float e1 = __builtin_amdgcn_exp2f(__fmaf_rn(q2, f.z, nm2));
        den1 += e1;  num1 = __fmaf_rn(e1, f.w, num1);
    }
    partN[tid] = num0 + num1;
    partD[tid] = den0 + den1;
    __syncthreads();
    if (tid < 64) {
        const float n = partN[tid] + partN[tid + 64] + partN[tid + 128] + partN[tid + 192];
        const float d = partD[tid] + partD[tid + 64] + partD[tid + 128] + partD[tid + 192];
        const int o = bh * 16384 + ks * 4096 + sub * 64 + tid;   // [bh][ks][q]
        PN[o] = n;
        PD[o] = d;
        PM[o] = m2;
    }
}

__global__ __launch_bounds__(128) void final_kernel(
    const float* __restrict__ x,
    const float* __restrict__ sc_w, const float* __restrict__ sc_b,
    const float* __restrict__ opw,  const float* __restrict__ opb,
    const float* __restrict__ ocw,  const float* __restrict__ ocb,
    const float* __restrict__ PN,   const float* __restrict__ PD,
    const float* __restrict__ PM,   float* __restrict__ out)
{
    const int g   = blockIdx.x * 128 + threadIdx.x;   // 0..8191
    const int b   = g >> 12;
    const int pix = g & 4095;
    const int y   = pix >> 6;
    const int xc  = pix & 63;

    float xin[4][3][3];
    #pragma unroll
    for (int ic = 0; ic < 4; ++ic)
        #pragma unroll
        for (int ky = 0; ky < 3; ++ky)
            #pragma unroll
            for (int kx = 0; kx < 3; ++kx) {
                const int yy = y + ky - 1, xx = xc + kx - 1;
                xin[ic][ky][kx] = (yy >= 0 && yy < 64 && xx >= 0 && xx < 64)
                                    ? x[(b * 4 + ic) * 4096 + yy * 64 + xx] : 0.f;
            }

    float sp[8];
    #pragma unroll
    for (int oc = 0; oc < 8; ++oc) {
        float a = sc_b[oc];
        #pragma unroll
        for (int ic = 0; ic < 4; ++ic)
            #pragma unroll
            for (int ky = 0; ky < 3; ++ky)
                #pragma unroll
                for (int kx = 0; kx < 3; ++kx)
                    a += sc_w[(oc * 4 + ic) * 9 + ky * 3 + kx] * xin[ic][ky][kx];
        sp[oc] = a;
    }

    // split-softmax merge: o = sum_s N_s 2^(m_s-M) / sum_s D_s 2^(m_s-M)
    float oh[4];
    #pragma unroll
    for (int h = 0; h < 4; ++h) {
        const int bh = b * 4 + h;
        float m2s[4];
        #pragma unroll
        for (int ks = 0; ks < 4; ++ks) m2s[ks] = PM[bh * 16384 + ks * 4096 + pix];
        const float M2 = fmaxf(fmaxf(m2s[0], m2s[1]), fmaxf(m2s[2], m2s[3]));
        float n = 0.f, d = 0.f;
        #pragma unroll
        for (int ks = 0; ks < 4; ++ks) {
            const float s = __builtin_amdgcn_exp2f(m2s[ks] - M2);   // <= 0 arg
            n = __fmaf_rn(PN[bh * 16384 + ks * 4096 + pix], s, n);
            d = __fmaf_rn(PD[bh * 16384 + ks * 4096 + pix], s, d);
        }
        oh[h] = n / d;
    }

    float w2[4];
    #pragma unroll
    for (int c = 0; c < 4; ++c)
        w2[c] = opb[c] + opw[c*4+0]*oh[0] + opw[c*4+1]*oh[1]
                       + opw[c*4+2]*oh[2] + opw[c*4+3]*oh[3];

    #pragma unroll
    for (int c = 0; c < 4; ++c) {
        float a = ocb[c];
        #pragma unroll
        for (int j = 0; j < 8; ++j) a += ocw[c * 12 + j] * sp[j];
        #pragma unroll
        for (int h = 0; h < 4; ++h) a += ocw[c * 12 + 8 + h] * w2[h];
        const int idx = (b * 4 + c) * 4096 + y * 64 + xc;
        out[idx] = 0.7f * x[idx] + 0.3f * a;
    }
}

extern "C" void kernel_launch(void* const* d_in, const int* in_sizes, int n_in,
                              void* d_out, int out_size, void* d_ws, size_t ws_size,
                              hipStream_t stream) {
    const float* x      = (const float*)d_in[0];
    const float* refl_w = (const float*)d_in[1];
    const float* refl_d = (const float*)d_in[2];
    const float* sc_w   = (const float*)d_in[3];
    const float* sc_b   = (const float*)d_in[4];
    const float* fb_w   = (const float*)d_in[5];
    const float* fb_b   = (const float*)d_in[6];
    const float* d1_w   = (const float*)d_in[7];
    const float* d1_b   = (const float*)d_in[8];
    const float* d2_w   = (const float*)d_in[9];
    const float* d2_b   = (const float*)d_in[10];
    const float* ipw    = (const float*)d_in[11];
    const float* ipb    = (const float*)d_in[12];
    const float* opw    = (const float*)d_in[13];
    const float* opb    = (const float*)d_in[14];
    const float* ocw    = (const float*)d_in[15];
    const float* ocb    = (const float*)d_in[16];
    float* out = (float*)d_out;

    // ws: Q | K | V (32768 each) | PN | PD | PM (131072 each)
    float* Q  = (float*)d_ws;
    float* K  = Q + 32768;
    float* V  = K + 32768;
    float* PN = V + 32768;
    float* PD = PN + 131072;
    float* PM = PD + 131072;

    reverb_qkv_kernel<<<dim3(64), dim3(1024), 0, stream>>>(
        x, refl_w, refl_d, fb_w, fb_b, d1_w, d1_b, d2_w, d2_b, ipw, ipb,
        Q, K, V);
    attn_kernel<<<dim3(2048), dim3(256), 0, stream>>>(Q, K, V, PN, PD, PM);
    final_kernel<<<dim3(64), dim3(128), 0, stream>>>(
        x, sc_w, sc_b, opw, opb, ocw, ocb, PN, PD, PM, out);
}

// Round 15
// 132.400 us; speedup vs baseline: 1.0698x; 1.0342x over previous
//
#include <hip/hip_runtime.h>
#include <math.h>

// ---------------------------------------------------------------------------
// LatentReverb: B=2, C=4, H=64, W=64.
// k1 (reverb): R12-exact column-slab redundant halo, 64 blocks x 1024 thr.
//   NEW: fb_w pre-transposed into LDS as WL[tap][ic][oc] -> each tap reads 4
//   contiguous float4 (ds_read_b128) instead of 16 serialized uniform loads.
// k2 (attn): head_dim=1, 4-way key split; 512 blocks x 512 thr; LDS KV;
//   4 QUERIES PER LANE (256-q chunks) -> 4x less LDS-pipe traffic; raw
//   v_exp_f32; split-local max; partial (N,D,m) to ws.
// k3: final = conv3x3 + split-softmax rescaled merge + out_proj + oc + mix.
// ---------------------------------------------------------------------------

#define ZERO4 make_float4(0.f, 0.f, 0.f, 0.f)

__device__ __forceinline__ float sigf(float v) { return 1.0f / (1.0f + __expf(-v)); }

// lane i <- lane i-1, lane 0 <- 0   [wave_shr:1]  == value at row r-1
__device__ __forceinline__ float dppL(float v) {
    return __int_as_float(__builtin_amdgcn_mov_dpp(__float_as_int(v), 0x138, 0xf, 0xf, true));
}
// lane i <- lane i+1, lane 63 <- 0  [wave_shl:1]  == value at row r+1
__device__ __forceinline__ float dppR(float v) {
    return __int_as_float(__builtin_amdgcn_mov_dpp(__float_as_int(v), 0x130, 0xf, 0xf, true));
}
__device__ __forceinline__ float4 shL4(float4 v) {   // row r-1 (zero at r=0)
    return make_float4(dppL(v.x), dppL(v.y), dppL(v.z), dppL(v.w));
}
__device__ __forceinline__ float4 shR4(float4 v) {   // row r+1 (zero at r=63)
    return make_float4(dppR(v.x), dppR(v.y), dppR(v.z), dppR(v.w));
}

// one 3x3 tap for all 4 oc x 4 ic, weights from LDS (transposed layout):
// w[ic] = float4(oc0..oc3) for this (tap, ic). Same expression tree as the
// global-memory version -> bit-identical results.
__device__ __forceinline__ void tapL(float4& a, const float4 t, const float4* w) {
    const float4 w0 = w[0], w1 = w[1], w2 = w[2], w3 = w[3];
    a.x += w0.x * t.x + w1.x * t.y + w2.x * t.z + w3.x * t.w;
    a.y += w0.y * t.x + w1.y * t.y + w2.y * t.z + w3.y * t.w;
    a.z += w0.z * t.x + w1.z * t.y + w2.z * t.z + w3.z * t.w;
    a.w += w0.w * t.x + w1.w * t.y + w2.w * t.z + w3.w * t.w;
}

__global__ __launch_bounds__(1024, 1) void reverb_qkv_kernel(
    const float* __restrict__ x,
    const float* __restrict__ refl_w,
    const float* __restrict__ refl_d,
    const float* __restrict__ fb_w,
    const float* __restrict__ fb_b,
    const float* __restrict__ d1_w,
    const float* __restrict__ d1_b,
    const float* __restrict__ d2_w,
    const float* __restrict__ d2_b,
    const float* __restrict__ ipw,
    const float* __restrict__ ipb,
    float* __restrict__ Qg, float* __restrict__ Kg, float* __restrict__ Vg)
{
    __shared__ float4 P [18 * 64];    // fb plane, local col-major: P[lc][row]
    __shared__ float4 BL[18 * 64];    // blurred plane
    __shared__ float4 WT[2 * 64];     // wet for the 2 owned cols
    __shared__ float  GT[3][8];       // gaussian tables
    __shared__ float  WL[9 * 16];     // fb_w transposed: WL[tap][ic][oc]

    const int blk   = blockIdx.x;
    const int batch = blk >> 5;          // 0..1
    const int own0  = (blk & 31) << 1;   // owned cols [own0, own0+2)
    const int LB    = own0 - 8;          // global col of local col 0
    const int tid   = threadIdx.x;
    const int wy    = tid >> 6;          // wave 0..15
    const int r     = tid & 63;          // lane == row

    // Gaussian tables (fp64, matches numpy K_TABLE after f32 rounding).
    if (tid < 3) {
        const int rr = tid + 1;
        const int ks = 2 * rr + 1;
        const int s  = (7 - ks) >> 1;
        const double step = 4.0 / (double)(ks - 1);
        double g[7]; double sum = 0.0;
        for (int t = 0; t < 7; ++t) {
            if (t < ks) { double u = -2.0 + step * (double)t; g[t] = exp(-u * u); sum += g[t]; }
        }
        for (int t = 0; t < 7; ++t) GT[tid][t] = 0.0f;
        for (int t = 0; t < ks; ++t) GT[tid][s + t] = (float)(g[t] / sum);
    }
    // transpose fb_w[oc][ic][tap] -> WL[tap*16 + ic*4 + oc]
    if (tid >= 64 && tid < 64 + 144) {
        const int idx = tid - 64;
        const int oc  = idx / 36;
        const int rem = idx - oc * 36;
        const int ic  = rem / 9;
        const int tp  = rem - ic * 9;
        WL[tp * 16 + ic * 4 + oc] = fb_w[idx];
    }

    // stage fb0 = 0.1*x, transposed into col-major local plane (zeros outside)
    for (int idx = tid; idx < 18 * 64; idx += 1024) {
        const int lc  = idx >> 6;
        const int row = idx & 63;
        const int gc  = LB + lc;
        float4 v = ZERO4;
        if (gc >= 0 && gc < 64) {
            const int base = batch * 16384 + row * 64 + gc;
            v.x = 0.1f * x[base];
            v.y = 0.1f * x[base + 4096];
            v.z = 0.1f * x[base + 8192];
            v.w = 0.1f * x[base + 12288];
        }
        P[idx] = v;
    }
    __syncthreads();

    const float4* WL4 = (const float4*)WL;    // WL4[tap*4 + ic]

    double w8 = 1.0;
    for (int j = 0; j < 8; ++j) {
        int kidx = (int)floorf(refl_d[j] * 0.5f);
        kidx = kidx < 0 ? 0 : (kidx > 3 ? 3 : kidx);
        float kv[7];
        #pragma unroll
        for (int u = 0; u < 7; ++u) {
            const float dv = (u == 3) ? 1.0f : 0.0f;
            kv[u] = (kidx == 0) ? dv : GT[kidx - 1][u];
        }
        const float wgt = sigf(refl_w[j]) * (float)w8;

        const int clo = max(0, own0 - (7 - j));
        const int chi = min(64, own0 + 2 + (7 - j));

        // ---- blur phase: only cols [clo-1, chi+1) ----
        const int lcA   = (clo - 1) - LB;            // >= 0
        const int nBlur = (chi + 1) - (clo - 1);     // <= 18
        for (int t = wy; t < nBlur; t += 16) {
            const int lc = lcA + t;
            const int gc = LB + lc;
            float4 b = ZERO4;
            if (gc >= 0 && gc < 64) {
                const float4 v  = P[lc * 64 + r];
                const float4 l1 = shL4(v),  l2 = shL4(l1), l3 = shL4(l2);
                const float4 r1 = shR4(v),  r2 = shR4(r1), r3 = shR4(r2);
                b.x = kv[0]*l3.x + kv[1]*l2.x + kv[2]*l1.x + kv[3]*v.x
                    + kv[4]*r1.x + kv[5]*r2.x + kv[6]*r3.x;
                b.y = kv[0]*l3.y + kv[1]*l2.y + kv[2]*l1.y + kv[3]*v.y
                    + kv[4]*r1.y + kv[5]*r2.y + kv[6]*r3.y;
                b.z = kv[0]*l3.z + kv[1]*l2.z + kv[2]*l1.z + kv[3]*v.z
                    + kv[4]*r1.z + kv[5]*r2.z + kv[6]*r3.z;
                b.w = kv[0]*l3.w + kv[1]*l2.w + kv[2]*l1.w + kv[3]*v.w
                    + kv[4]*r1.w + kv[5]*r2.w + kv[6]*r3.w;
            }
            BL[lc * 64 + r] = b;
        }
        __syncthreads();

        // ---- conv+MLP phase: <=1 col per wave ----
        const int c = clo + wy;
        if (wy < chi - clo) {                    // wave-uniform
            const int lc = c - LB;               // 1..16
            const float4 bm = BL[(lc - 1) * 64 + r];
            const float4 bc = BL[lc * 64 + r];
            const float4 bp = BL[(lc + 1) * 64 + r];

            float4 acc = make_float4(fb_b[0], fb_b[1], fb_b[2], fb_b[3]);
            tapL(acc, shL4(bm), WL4 + 0*4);  tapL(acc, shL4(bc), WL4 + 1*4);  tapL(acc, shL4(bp), WL4 + 2*4);
            tapL(acc, bm,       WL4 + 3*4);  tapL(acc, bc,       WL4 + 4*4);  tapL(acc, bp,       WL4 + 5*4);
            tapL(acc, shR4(bm), WL4 + 6*4);  tapL(acc, shR4(bc), WL4 + 7*4);  tapL(acc, shR4(bp), WL4 + 8*4);

            // damp MLP
            float4 rr = acc;
            float h0 = d1_b[0] + d1_w[0]*rr.x + d1_w[1]*rr.y + d1_w[2]*rr.z + d1_w[3]*rr.w;
            float h1 = d1_b[1] + d1_w[4]*rr.x + d1_w[5]*rr.y + d1_w[6]*rr.z + d1_w[7]*rr.w;
            h0 = h0 * sigf(h0);
            h1 = h1 * sigf(h1);
            const float d0  = sigf(d2_b[0] + d2_w[0]*h0 + d2_w[1]*h1);
            const float d1v = sigf(d2_b[1] + d2_w[2]*h0 + d2_w[3]*h1);
            const float d2v = sigf(d2_b[2] + d2_w[4]*h0 + d2_w[5]*h1);
            const float d3v = sigf(d2_b[3] + d2_w[6]*h0 + d2_w[7]*h1);
            rr.x *= d0; rr.y *= d1v; rr.z *= d2v; rr.w *= d3v;

            // fb update (in place; only this wave touches col lc this phase)
            const float4 oldfb = P[lc * 64 + r];
            P[lc * 64 + r] = make_float4(oldfb.x + 0.04f*rr.x, oldfb.y + 0.04f*rr.y,
                                         oldfb.z + 0.04f*rr.z, oldfb.w + 0.04f*rr.w);

            // wet update for owned cols
            if (c >= own0 && c < own0 + 2) {
                const int widx = (c - own0) * 64 + r;
                float4 wv = make_float4(wgt*rr.x, wgt*rr.y, wgt*rr.z, wgt*rr.w);
                if (j > 0) {
                    const float4 old = WT[widx];
                    wv.x += old.x; wv.y += old.y; wv.z += old.z; wv.w += old.w;
                }
                WT[widx] = wv;
            }
        }
        __syncthreads();
        w8 *= 0.8;
    }

    // ---- epilogue: qkv = in_proj(wet) for the 2 owned cols ----
    if (tid < 128) {
        const int row = tid & 63;
        const int oc  = tid >> 6;
        const int c   = own0 + oc;
        const float4 wv = WT[oc * 64 + row];
        #pragma unroll
        for (int h = 0; h < 4; ++h) {
            const float q = ipb[h]
                + ipw[h*4+0]*wv.x + ipw[h*4+1]*wv.y
                + ipw[h*4+2]*wv.z + ipw[h*4+3]*wv.w;
            const float k = ipb[4+h]
                + ipw[(4+h)*4+0]*wv.x + ipw[(4+h)*4+1]*wv.y
                + ipw[(4+h)*4+2]*wv.z + ipw[(4+h)*4+3]*wv.w;
            const float v = ipb[8+h]
                + ipw[(8+h)*4+0]*wv.x + ipw[(8+h)*4+1]*wv.y
                + ipw[(8+h)*4+2]*wv.z + ipw[(8+h)*4+3]*wv.w;
            const int o = (batch * 4 + h) * 4096 + row * 64 + c;
            Qg[o] = q; Kg[o] = k; Vg[o] = v;
        }
    }
}

// 512 blocks x 512 thr: (bh, 256-q chunk, ksplit). LDS KV (1024-key split);
// 8 waves = 8 key-eighths (128 keys each); 4 QUERIES PER LANE -> each b128
// KV read feeds 8 exp ops (4x less LDS traffic than 1 q/lane).
__global__ __launch_bounds__(512) void attn_kernel(
    const float* __restrict__ Qg, const float* __restrict__ Kg,
    const float* __restrict__ Vg,
    float* __restrict__ PN, float* __restrict__ PD, float* __restrict__ PM)
{
    __shared__ float2 KV[1024];               // 8 KB interleaved (k,v)
    __shared__ float  wred[16];
    __shared__ float  pN[4][512], pD[4][512]; // 16 KB partials

    const int bh  = blockIdx.x >> 6;          // 0..7
    const int sub = (blockIdx.x >> 2) & 15;   // 256-query chunk
    const int ks  = blockIdx.x & 3;           // key split
    const int tid = threadIdx.x;

    const float* Kp = Kg + bh * 4096 + ks * 1024;
    const float* Vp = Vg + bh * 4096 + ks * 1024;

    // stage split into LDS + split-local kmax/kmin
    float pmax = -3.0e38f, pmin = 3.0e38f;
    #pragma unroll
    for (int t = tid; t < 1024; t += 512) {
        const float kk = Kp[t];
        const float vv = Vp[t];
        KV[t] = make_float2(kk, vv);
        pmax = fmaxf(pmax, kk);
        pmin = fminf(pmin, kk);
    }
    #pragma unroll
    for (int off = 32; off > 0; off >>= 1) {
        pmax = fmaxf(pmax, __shfl_xor(pmax, off, 64));
        pmin = fminf(pmin, __shfl_xor(pmin, off, 64));
    }
    if ((tid & 63) == 0) { wred[tid >> 6] = pmax; wred[8 + (tid >> 6)] = pmin; }
    __syncthreads();
    float kmax = wred[0], kmin = wred[8];
    #pragma unroll
    for (int w = 1; w < 8; ++w) {
        kmax = fmaxf(kmax, wred[w]);
        kmin = fminf(kmin, wred[8 + w]);
    }

    const int ql = tid & 63;
    const int kh = __builtin_amdgcn_readfirstlane(tid >> 6);   // wave 0..7

    const float L2E = 1.4426950408889634f;
    float q2[4], nm2[4];
    #pragma unroll
    for (int t = 0; t < 4; ++t) {
        const float q = Qg[bh * 4096 + sub * 256 + ql + 64 * t];
        q2[t]  = q * L2E;
        nm2[t] = -(((q >= 0.0f) ? q * kmax : q * kmin) * L2E);
    }

    // per-wave 128 keys = 64 float4 of (k0,v0,k1,v1)
    const float4* KV4 = (const float4*)KV;
    const int base4 = kh * 64;

    float num[4] = {0.f, 0.f, 0.f, 0.f};
    float den[4] = {0.f, 0.f, 0.f, 0.f};
    #pragma unroll 8
    for (int j = 0; j < 64; ++j) {
        const float4 f = KV4[base4 + j];      // broadcast ds_read_b128
        #pragma unroll
        for (int t = 0; t < 4; ++t) {
            const float e0 = __builtin_amdgcn_exp2f(__fmaf_rn(q2[t], f.x, nm2[t]));
            den[t] += e0;  num[t] = __fmaf_rn(e0, f.y, num[t]);
            const float e1 = __builtin_amdgcn_exp2f(__fmaf_rn(q2[t], f.z, nm2[t]));
            den[t] += e1;  num[t] = __fmaf_rn(e1, f.w, num[t]);
        }
    }
    #pragma unroll
    for (int t = 0; t < 4; ++t) {
        pN[t][tid] = num[t];
        pD[t][tid] = den[t];
    }
    __syncthreads();
    if (tid < 256) {
        const int which = tid >> 6;          // query sub-group 0..3
        const int qa    = tid & 63;
        float n = 0.f, d = 0.f;
        #pragma unroll
        for (int w = 0; w < 8; ++w) {
            n += pN[which][w * 64 + qa];
            d += pD[which][w * 64 + qa];
        }
        const int qi = sub * 256 + tid;      // == sub*256 + which*64 + qa
        const int o  = bh * 16384 + ks * 4096 + qi;
        PN[o] = n;
        PD[o] = d;
        const float q = Qg[bh * 4096 + qi];
        PM[o] = ((q >= 0.0f) ? q * kmax : q * kmin) * L2E;
    }
}

__global__ __launch_bounds__(128) void final_kernel(
    const float* __restrict__ x,
    const float* __restrict__ sc_w, const float* __restrict__ sc_b,
    const float* __restrict__ opw,  const float* __restrict__ opb,
    const float* __restrict__ ocw,  const float* __restrict__ ocb,
    const float* __restrict__ PN,   const float* __restrict__ PD,
    const float* __restrict__ PM,   float* __restrict__ out)
{
    const int g   = blockIdx.x * 128 + threadIdx.x;   // 0..8191
    const int b   = g >> 12;
    const int pix = g & 4095;
    const int y   = pix >> 6;
    const int xc  = pix & 63;

    float xin[4][3][3];
    #pragma unroll
    for (int ic = 0; ic < 4; ++ic)
        #pragma unroll
        for (int ky = 0; ky < 3; ++ky)
            #pragma unroll
            for (int kx = 0; kx < 3; ++kx) {
                const int yy = y + ky - 1, xx = xc + kx - 1;
                xin[ic][ky][kx] = (yy >= 0 && yy < 64 && xx >= 0 && xx < 64)
                                    ? x[(b * 4 + ic) * 4096 + yy * 64 + xx] : 0.f;
            }

    float sp[8];
    #pragma unroll
    for (int oc = 0; oc < 8; ++oc) {
        float a = sc_b[oc];
        #pragma unroll
        for (int ic = 0; ic < 4; ++ic)
            #pragma unroll
            for (int ky = 0; ky < 3; ++ky)
                #pragma unroll
                for (int kx = 0; kx < 3; ++kx)
                    a += sc_w[(oc * 4 + ic) * 9 + ky * 3 + kx] * xin[ic][ky][kx];
        sp[oc] = a;
    }

    // split-softmax merge: o = sum_s N_s 2^(m_s-M) / sum_s D_s 2^(m_s-M)
    float oh[4];
    #pragma unroll
    for (int h = 0; h < 4; ++h) {
        const int bh = b * 4 + h;
        float m2s[4];
        #pragma unroll
        for (int ks = 0; ks < 4; ++ks) m2s[ks] = PM[bh * 16384 + ks * 4096 + pix];
        const float M2 = fmaxf(fmaxf(m2s[0], m2s[1]), fmaxf(m2s[2], m2s[3]));
        float n = 0.f, d = 0.f;
        #pragma unroll
        for (int ks = 0; ks < 4; ++ks) {
            const float s = __builtin_amdgcn_exp2f(m2s[ks] - M2);   // <= 0 arg
            n = __fmaf_rn(PN[bh * 16384 + ks * 4096 + pix], s, n);
            d = __fmaf_rn(PD[bh * 16384 + ks * 4096 + pix], s, d);
        }
        oh[h] = n / d;
    }

    float w2[4];
    #pragma unroll
    for (int c = 0; c < 4; ++c)
        w2[c] = opb[c] + opw[c*4+0]*oh[0] + opw[c*4+1]*oh[1]
                       + opw[c*4+2]*oh[2] + opw[c*4+3]*oh[3];

    #pragma unroll
    for (int c = 0; c < 4; ++c) {
        float a = ocb[c];
        #pragma unroll
        for (int j = 0; j < 8; ++j) a += ocw[c * 12 + j] * sp[j];
        #pragma unroll
        for (int h = 0; h < 4; ++h) a += ocw[c * 12 + 8 + h] * w2[h];
        const int idx = (b * 4 + c) * 4096 + y * 64 + xc;
        out[idx] = 0.7f * x[idx] + 0.3f * a;
    }
}

extern "C" void kernel_launch(void* const* d_in, const int* in_sizes, int n_in,
                              void* d_out, int out_size, void* d_ws, size_t ws_size,
                              hipStream_t stream) {
    const float* x      = (const float*)d_in[0];
    const float* refl_w = (const float*)d_in[1];
    const float* refl_d = (const float*)d_in[2];
    const float* sc_w   = (const float*)d_in[3];
    const float* sc_b   = (const float*)d_in[4];
    const float* fb_w   = (const float*)d_in[5];
    const float* fb_b   = (const float*)d_in[6];
    const float* d1_w   = (const float*)d_in[7];
    const float* d1_b   = (const float*)d_in[8];
    const float* d2_w   = (const float*)d_in[9];
    const float* d2_b   = (const float*)d_in[10];
    const float* ipw    = (const float*)d_in[11];
    const float* ipb    = (const float*)d_in[12];
    const float* opw    = (const float*)d_in[13];
    const float* opb    = (const float*)d_in[14];
    const float* ocw    = (const float*)d_in[15];
    const float* ocb    = (const float*)d_in[16];
    float* out = (float*)d_out;

    // ws: Q | K | V (32768 each) | PN | PD | PM (131072 each)
    float* Q  = (float*)d_ws;
    float* K  = Q + 32768;
    float* V  = K + 32768;
    float* PN = V + 32768;
    float* PD = PN + 131072;
    float* PM = PD + 131072;

    reverb_qkv_kernel<<<dim3(64), dim3(1024), 0, stream>>>(
        x, refl_w, refl_d, fb_w, fb_b, d1_w, d1_b, d2_w, d2_b, ipw, ipb,
        Q, K, V);
    attn_kernel<<<dim3(512), dim3(512), 0, stream>>>(Q, K, V, PN, PD, PM);
    final_kernel<<<dim3(64), dim3(128), 0, stream>>>(
        x, sc_w, sc_b, opw, opb, ocw, ocb, PN, PD, PM, out);
}

// Round 16
// 130.639 us; speedup vs baseline: 1.0842x; 1.0135x over previous
//
#include <hip/hip_runtime.h>
#include <math.h>

// ---------------------------------------------------------------------------
// LatentReverb: B=2, C=4, H=64, W=64.
// k1 (reverb): column-slab redundant halo, lanes = rows. 128 blocks = 2 batch
//   x 64 SINGLE-col slabs x 1024 thr (16 waves) -> 1 col/wave/iter (same as
//   R15) but 2x CUs. fb_w transposed in LDS (WL). 17-col LDS window.
// k2 (attn): head_dim=1, 4-way key split; 512 blocks x 512 thr; LDS KV;
//   4 queries/lane; raw v_exp_f32; split-local max; partial (N,D,m) to ws.
// k3: final = conv3x3 + split-softmax rescaled merge + out_proj + oc + mix.
// ---------------------------------------------------------------------------

#define ZERO4 make_float4(0.f, 0.f, 0.f, 0.f)

__device__ __forceinline__ float sigf(float v) { return 1.0f / (1.0f + __expf(-v)); }

// lane i <- lane i-1, lane 0 <- 0   [wave_shr:1]  == value at row r-1
__device__ __forceinline__ float dppL(float v) {
    return __int_as_float(__builtin_amdgcn_mov_dpp(__float_as_int(v), 0x138, 0xf, 0xf, true));
}
// lane i <- lane i+1, lane 63 <- 0  [wave_shl:1]  == value at row r+1
__device__ __forceinline__ float dppR(float v) {
    return __int_as_float(__builtin_amdgcn_mov_dpp(__float_as_int(v), 0x130, 0xf, 0xf, true));
}
__device__ __forceinline__ float4 shL4(float4 v) {   // row r-1 (zero at r=0)
    return make_float4(dppL(v.x), dppL(v.y), dppL(v.z), dppL(v.w));
}
__device__ __forceinline__ float4 shR4(float4 v) {   // row r+1 (zero at r=63)
    return make_float4(dppR(v.x), dppR(v.y), dppR(v.z), dppR(v.w));
}

// one 3x3 tap for all 4 oc x 4 ic, weights from LDS (transposed layout):
// w[ic] = float4(oc0..oc3) for this (tap, ic). Same expression tree as the
// global-memory version -> bit-identical results.
__device__ __forceinline__ void tapL(float4& a, const float4 t, const float4* w) {
    const float4 w0 = w[0], w1 = w[1], w2 = w[2], w3 = w[3];
    a.x += w0.x * t.x + w1.x * t.y + w2.x * t.z + w3.x * t.w;
    a.y += w0.y * t.x + w1.y * t.y + w2.y * t.z + w3.y * t.w;
    a.z += w0.z * t.x + w1.z * t.y + w2.z * t.z + w3.z * t.w;
    a.w += w0.w * t.x + w1.w * t.y + w2.w * t.z + w3.w * t.w;
}

__global__ __launch_bounds__(1024, 1) void reverb_qkv_kernel(
    const float* __restrict__ x,
    const float* __restrict__ refl_w,
    const float* __restrict__ refl_d,
    const float* __restrict__ fb_w,
    const float* __restrict__ fb_b,
    const float* __restrict__ d1_w,
    const float* __restrict__ d1_b,
    const float* __restrict__ d2_w,
    const float* __restrict__ d2_b,
    const float* __restrict__ ipw,
    const float* __restrict__ ipb,
    float* __restrict__ Qg, float* __restrict__ Kg, float* __restrict__ Vg)
{
    __shared__ float4 P [17 * 64];    // fb plane, local col-major: P[lc][row]
    __shared__ float4 BL[17 * 64];    // blurred plane
    __shared__ float4 WT[64];         // wet for the owned col
    __shared__ float  GT[3][8];       // gaussian tables
    __shared__ float  WL[9 * 16];     // fb_w transposed: WL[tap][ic][oc]

    const int blk   = blockIdx.x;        // 128 blocks
    const int batch = blk >> 6;          // 0..1
    const int c0    = blk & 63;          // owned column
    const int LB    = c0 - 8;            // global col of local col 0
    const int tid   = threadIdx.x;
    const int wy    = tid >> 6;          // wave 0..15
    const int r     = tid & 63;          // lane == row

    // Gaussian tables (fp64, matches numpy K_TABLE after f32 rounding).
    if (tid < 3) {
        const int rr = tid + 1;
        const int ks = 2 * rr + 1;
        const int s  = (7 - ks) >> 1;
        const double step = 4.0 / (double)(ks - 1);
        double g[7]; double sum = 0.0;
        for (int t = 0; t < 7; ++t) {
            if (t < ks) { double u = -2.0 + step * (double)t; g[t] = exp(-u * u); sum += g[t]; }
        }
        for (int t = 0; t < 7; ++t) GT[tid][t] = 0.0f;
        for (int t = 0; t < ks; ++t) GT[tid][s + t] = (float)(g[t] / sum);
    }
    // transpose fb_w[oc][ic][tap] -> WL[tap*16 + ic*4 + oc]
    if (tid >= 64 && tid < 64 + 144) {
        const int idx = tid - 64;
        const int oc  = idx / 36;
        const int rem = idx - oc * 36;
        const int ic  = rem / 9;
        const int tp  = rem - ic * 9;
        WL[tp * 16 + ic * 4 + oc] = fb_w[idx];
    }

    // stage fb0 = 0.1*x, transposed into col-major local plane (zeros outside)
    for (int idx = tid; idx < 17 * 64; idx += 1024) {
        const int lc  = idx >> 6;
        const int row = idx & 63;
        const int gc  = LB + lc;
        float4 v = ZERO4;
        if (gc >= 0 && gc < 64) {
            const int base = batch * 16384 + row * 64 + gc;
            v.x = 0.1f * x[base];
            v.y = 0.1f * x[base + 4096];
            v.z = 0.1f * x[base + 8192];
            v.w = 0.1f * x[base + 12288];
        }
        P[idx] = v;
    }
    __syncthreads();

    const float4* WL4 = (const float4*)WL;    // WL4[tap*4 + ic]

    double w8 = 1.0;
    for (int j = 0; j < 8; ++j) {
        int kidx = (int)floorf(refl_d[j] * 0.5f);
        kidx = kidx < 0 ? 0 : (kidx > 3 ? 3 : kidx);
        float kv[7];
        #pragma unroll
        for (int u = 0; u < 7; ++u) {
            const float dv = (u == 3) ? 1.0f : 0.0f;
            kv[u] = (kidx == 0) ? dv : GT[kidx - 1][u];
        }
        const float wgt = sigf(refl_w[j]) * (float)w8;

        const int rad = 7 - j;
        const int clo = max(0, c0 - rad);
        const int chi = min(64, c0 + 1 + rad);       // conv cols [clo, chi)

        // ---- blur phase: cols [clo-1, chi] (nBlur <= 17) ----
        const int lcA   = (clo - 1) - LB;            // >= 0
        const int nBlur = (chi + 1) - (clo - 1);
        for (int t = wy; t < nBlur; t += 16) {
            const int lc = lcA + t;
            const int gc = LB + lc;
            float4 b = ZERO4;
            if (gc >= 0 && gc < 64) {
                const float4 v  = P[lc * 64 + r];
                const float4 l1 = shL4(v),  l2 = shL4(l1), l3 = shL4(l2);
                const float4 r1 = shR4(v),  r2 = shR4(r1), r3 = shR4(r2);
                b.x = kv[0]*l3.x + kv[1]*l2.x + kv[2]*l1.x + kv[3]*v.x
                    + kv[4]*r1.x + kv[5]*r2.x + kv[6]*r3.x;
                b.y = kv[0]*l3.y + kv[1]*l2.y + kv[2]*l1.y + kv[3]*v.y
                    + kv[4]*r1.y + kv[5]*r2.y + kv[6]*r3.y;
                b.z = kv[0]*l3.z + kv[1]*l2.z + kv[2]*l1.z + kv[3]*v.z
                    + kv[4]*r1.z + kv[5]*r2.z + kv[6]*r3.z;
                b.w = kv[0]*l3.w + kv[1]*l2.w + kv[2]*l1.w + kv[3]*v.w
                    + kv[4]*r1.w + kv[5]*r2.w + kv[6]*r3.w;
            }
            BL[lc * 64 + r] = b;
        }
        __syncthreads();

        // ---- conv+MLP phase: <=1 col per wave (chi-clo <= 15) ----
        const int c = clo + wy;
        if (wy < chi - clo) {                    // wave-uniform
            const int lc = c - LB;               // 1..15
            const float4 bm = BL[(lc - 1) * 64 + r];
            const float4 bc = BL[lc * 64 + r];
            const float4 bp = BL[(lc + 1) * 64 + r];

            float4 acc = make_float4(fb_b[0], fb_b[1], fb_b[2], fb_b[3]);
            tapL(acc, shL4(bm), WL4 + 0*4);  tapL(acc, shL4(bc), WL4 + 1*4);  tapL(acc, shL4(bp), WL4 + 2*4);
            tapL(acc, bm,       WL4 + 3*4);  tapL(acc, bc,       WL4 + 4*4);  tapL(acc, bp,       WL4 + 5*4);
            tapL(acc, shR4(bm), WL4 + 6*4);  tapL(acc, shR4(bc), WL4 + 7*4);  tapL(acc, shR4(bp), WL4 + 8*4);

            // damp MLP
            float4 rr = acc;
            float h0 = d1_b[0] + d1_w[0]*rr.x + d1_w[1]*rr.y + d1_w[2]*rr.z + d1_w[3]*rr.w;
            float h1 = d1_b[1] + d1_w[4]*rr.x + d1_w[5]*rr.y + d1_w[6]*rr.z + d1_w[7]*rr.w;
            h0 = h0 * sigf(h0);
            h1 = h1 * sigf(h1);
            const float d0  = sigf(d2_b[0] + d2_w[0]*h0 + d2_w[1]*h1);
            const float d1v = sigf(d2_b[1] + d2_w[2]*h0 + d2_w[3]*h1);
            const float d2v = sigf(d2_b[2] + d2_w[4]*h0 + d2_w[5]*h1);
            const float d3v = sigf(d2_b[3] + d2_w[6]*h0 + d2_w[7]*h1);
            rr.x *= d0; rr.y *= d1v; rr.z *= d2v; rr.w *= d3v;

            // fb update (in place; only this wave touches col lc this phase)
            const float4 oldfb = P[lc * 64 + r];
            P[lc * 64 + r] = make_float4(oldfb.x + 0.04f*rr.x, oldfb.y + 0.04f*rr.y,
                                         oldfb.z + 0.04f*rr.z, oldfb.w + 0.04f*rr.w);

            // wet update for owned col
            if (c == c0) {
                float4 wv = make_float4(wgt*rr.x, wgt*rr.y, wgt*rr.z, wgt*rr.w);
                if (j > 0) {
                    const float4 old = WT[r];
                    wv.x += old.x; wv.y += old.y; wv.z += old.z; wv.w += old.w;
                }
                WT[r] = wv;
            }
        }
        __syncthreads();
        w8 *= 0.8;
    }

    // ---- epilogue: qkv = in_proj(wet) for the owned col ----
    if (tid < 64) {
        const float4 wv = WT[tid];
        #pragma unroll
        for (int h = 0; h < 4; ++h) {
            const float q = ipb[h]
                + ipw[h*4+0]*wv.x + ipw[h*4+1]*wv.y
                + ipw[h*4+2]*wv.z + ipw[h*4+3]*wv.w;
            const float k = ipb[4+h]
                + ipw[(4+h)*4+0]*wv.x + ipw[(4+h)*4+1]*wv.y
                + ipw[(4+h)*4+2]*wv.z + ipw[(4+h)*4+3]*wv.w;
            const float v = ipb[8+h]
                + ipw[(8+h)*4+0]*wv.x + ipw[(8+h)*4+1]*wv.y
                + ipw[(8+h)*4+2]*wv.z + ipw[(8+h)*4+3]*wv.w;
            const int o = (batch * 4 + h) * 4096 + tid * 64 + c0;
            Qg[o] = q; Kg[o] = k; Vg[o] = v;
        }
    }
}

// 512 blocks x 512 thr: (bh, 256-q chunk, ksplit). LDS KV (1024-key split);
// 8 waves = 8 key-eighths (128 keys each); 4 queries per lane.
__global__ __launch_bounds__(512) void attn_kernel(
    const float* __restrict__ Qg, const float* __restrict__ Kg,
    const float* __restrict__ Vg,
    float* __restrict__ PN, float* __restrict__ PD, float* __restrict__ PM)
{
    __shared__ float2 KV[1024];               // 8 KB interleaved (k,v)
    __shared__ float  wred[16];
    __shared__ float  pN[4][512], pD[4][512]; // 16 KB partials

    const int bh  = blockIdx.x >> 6;          // 0..7
    const int sub = (blockIdx.x >> 2) & 15;   // 256-query chunk
    const int ks  = blockIdx.x & 3;           // key split
    const int tid = threadIdx.x;

    const float* Kp = Kg + bh * 4096 + ks * 1024;
    const float* Vp = Vg + bh * 4096 + ks * 1024;

    // stage split into LDS + split-local kmax/kmin
    float pmax = -3.0e38f, pmin = 3.0e38f;
    #pragma unroll
    for (int t = tid; t < 1024; t += 512) {
        const float kk = Kp[t];
        const float vv = Vp[t];
        KV[t] = make_float2(kk, vv);
        pmax = fmaxf(pmax, kk);
        pmin = fminf(pmin, kk);
    }
    #pragma unroll
    for (int off = 32; off > 0; off >>= 1) {
        pmax = fmaxf(pmax, __shfl_xor(pmax, off, 64));
        pmin = fminf(pmin, __shfl_xor(pmin, off, 64));
    }
    if ((tid & 63) == 0) { wred[tid >> 6] = pmax; wred[8 + (tid >> 6)] = pmin; }
    __syncthreads();
    float kmax = wred[0], kmin = wred[8];
    #pragma unroll
    for (int w = 1; w < 8; ++w) {
        kmax = fmaxf(kmax, wred[w]);
        kmin = fminf(kmin, wred[8 + w]);
    }

    const int ql = tid & 63;
    const int kh = __builtin_amdgcn_readfirstlane(tid >> 6);   // wave 0..7

    const float L2E = 1.4426950408889634f;
    float q2[4], nm2[4];
    #pragma unroll
    for (int t = 0; t < 4; ++t) {
        const float q = Qg[bh * 4096 + sub * 256 + ql + 64 * t];
        q2[t]  = q * L2E;
        nm2[t] = -(((q >= 0.0f) ? q * kmax : q * kmin) * L2E);
    }

    // per-wave 128 keys = 64 float4 of (k0,v0,k1,v1)
    const float4* KV4 = (const float4*)KV;
    const int base4 = kh * 64;

    float num[4] = {0.f, 0.f, 0.f, 0.f};
    float den[4] = {0.f, 0.f, 0.f, 0.f};
    #pragma unroll 8
    for (int j = 0; j < 64; ++j) {
        const float4 f = KV4[base4 + j];      // broadcast ds_read_b128
        #pragma unroll
        for (int t = 0; t < 4; ++t) {
            const float e0 = __builtin_amdgcn_exp2f(__fmaf_rn(q2[t], f.x, nm2[t]));
            den[t] += e0;  num[t] = __fmaf_rn(e0, f.y, num[t]);
            const float e1 = __builtin_amdgcn_exp2f(__fmaf_rn(q2[t], f.z, nm2[t]));
            den[t] += e1;  num[t] = __fmaf_rn(e1, f.w, num[t]);
        }
    }
    #pragma unroll
    for (int t = 0; t < 4; ++t) {
        pN[t][tid] = num[t];
        pD[t][tid] = den[t];
    }
    __syncthreads();
    if (tid < 256) {
        const int which = tid >> 6;          // query sub-group 0..3
        const int qa    = tid & 63;
        float n = 0.f, d = 0.f;
        #pragma unroll
        for (int w = 0; w < 8; ++w) {
            n += pN[which][w * 64 + qa];
            d += pD[which][w * 64 + qa];
        }
        const int qi = sub * 256 + tid;      // == sub*256 + which*64 + qa
        const int o  = bh * 16384 + ks * 4096 + qi;
        PN[o] = n;
        PD[o] = d;
        const float q = Qg[bh * 4096 + qi];
        PM[o] = ((q >= 0.0f) ? q * kmax : q * kmin) * L2E;
    }
}

__global__ __launch_bounds__(128) void final_kernel(
    const float* __restrict__ x,
    const float* __restrict__ sc_w, const float* __restrict__ sc_b,
    const float* __restrict__ opw,  const float* __restrict__ opb,
    const float* __restrict__ ocw,  const float* __restrict__ ocb,
    const float* __restrict__ PN,   const float* __restrict__ PD,
    const float* __restrict__ PM,   float* __restrict__ out)
{
    const int g   = blockIdx.x * 128 + threadIdx.x;   // 0..8191
    const int b   = g >> 12;
    const int pix = g & 4095;
    const int y   = pix >> 6;
    const int xc  = pix & 63;

    float xin[4][3][3];
    #pragma unroll
    for (int ic = 0; ic < 4; ++ic)
        #pragma unroll
        for (int ky = 0; ky < 3; ++ky)
            #pragma unroll
            for (int kx = 0; kx < 3; ++kx) {
                const int yy = y + ky - 1, xx = xc + kx - 1;
                xin[ic][ky][kx] = (yy >= 0 && yy < 64 && xx >= 0 && xx < 64)
                                    ? x[(b * 4 + ic) * 4096 + yy * 64 + xx] : 0.f;
            }

    float sp[8];
    #pragma unroll
    for (int oc = 0; oc < 8; ++oc) {
        float a = sc_b[oc];
        #pragma unroll
        for (int ic = 0; ic < 4; ++ic)
            #pragma unroll
            for (int ky = 0; ky < 3; ++ky)
                #pragma unroll
                for (int kx = 0; kx < 3; ++kx)
                    a += sc_w[(oc * 4 + ic) * 9 + ky * 3 + kx] * xin[ic][ky][kx];
        sp[oc] = a;
    }

    // split-softmax merge: o = sum_s N_s 2^(m_s-M) / sum_s D_s 2^(m_s-M)
    float oh[4];
    #pragma unroll
    for (int h = 0; h < 4; ++h) {
        const int bh = b * 4 + h;
        float m2s[4];
        #pragma unroll
        for (int ks = 0; ks < 4; ++ks) m2s[ks] = PM[bh * 16384 + ks * 4096 + pix];
        const float M2 = fmaxf(fmaxf(m2s[0], m2s[1]), fmaxf(m2s[2], m2s[3]));
        float n = 0.f, d = 0.f;
        #pragma unroll
        for (int ks = 0; ks < 4; ++ks) {
            const float s = __builtin_amdgcn_exp2f(m2s[ks] - M2);   // <= 0 arg
            n = __fmaf_rn(PN[bh * 16384 + ks * 4096 + pix], s, n);
            d = __fmaf_rn(PD[bh * 16384 + ks * 4096 + pix], s, d);
        }
        oh[h] = n / d;
    }

    float w2[4];
    #pragma unroll
    for (int c = 0; c < 4; ++c)
        w2[c] = opb[c] + opw[c*4+0]*oh[0] + opw[c*4+1]*oh[1]
                       + opw[c*4+2]*oh[2] + opw[c*4+3]*oh[3];

    #pragma unroll
    for (int c = 0; c < 4; ++c) {
        float a = ocb[c];
        #pragma unroll
        for (int j = 0; j < 8; ++j) a += ocw[c * 12 + j] * sp[j];
        #pragma unroll
        for (int h = 0; h < 4; ++h) a += ocw[c * 12 + 8 + h] * w2[h];
        const int idx = (b * 4 + c) * 4096 + y * 64 + xc;
        out[idx] = 0.7f * x[idx] + 0.3f * a;
    }
}

extern "C" void kernel_launch(void* const* d_in, const int* in_sizes, int n_in,
                              void* d_out, int out_size, void* d_ws, size_t ws_size,
                              hipStream_t stream) {
    const float* x      = (const float*)d_in[0];
    const float* refl_w = (const float*)d_in[1];
    const float* refl_d = (const float*)d_in[2];
    const float* sc_w   = (const float*)d_in[3];
    const float* sc_b   = (const float*)d_in[4];
    const float* fb_w   = (const float*)d_in[5];
    const float* fb_b   = (const float*)d_in[6];
    const float* d1_w   = (const float*)d_in[7];
    const float* d1_b   = (const float*)d_in[8];
    const float* d2_w   = (const float*)d_in[9];
    const float* d2_b   = (const float*)d_in[10];
    const float* ipw    = (const float*)d_in[11];
    const float* ipb    = (const float*)d_in[12];
    const float* opw    = (const float*)d_in[13];
    const float* opb    = (const float*)d_in[14];
    const float* ocw    = (const float*)d_in[15];
    const float* ocb    = (const float*)d_in[16];
    float* out = (float*)d_out;

    // ws: Q | K | V (32768 each) | PN | PD | PM (131072 each)
    float* Q  = (float*)d_ws;
    float* K  = Q + 32768;
    float* V  = K + 32768;
    float* PN = V + 32768;
    float* PD = PN + 131072;
    float* PM = PD + 131072;

    reverb_qkv_kernel<<<dim3(128), dim3(1024), 0, stream>>>(
        x, refl_w, refl_d, fb_w, fb_b, d1_w, d1_b, d2_w, d2_b, ipw, ipb,
        Q, K, V);
    attn_kernel<<<dim3(512), dim3(512), 0, stream>>>(Q, K, V, PN, PD, PM);
    final_kernel<<<dim3(64), dim3(128), 0, stream>>>(
        x, sc_w, sc_b, opw, opb, ocw, ocb, PN, PD, PM, out);
}